// Round 10
// baseline (311.196 us; speedup 1.0000x reference)
//
#include <hip/hip_runtime.h>

#define NN 128

__constant__ int E_l [15] = {0,0,0, 1,1,1,1,1,1, 2,2,2,2,2,2};
__constant__ int E_l1[15] = {0,1,2, 0,1,1,1,2,2, 0,1,1,2,2,2};
__constant__ int E_l2[15] = {0,1,2, 1,0,1,2,1,2, 2,1,2,0,1,2};
__constant__ int E_cg[15] = {0,1,10, 35,44,53,80,125,170, 245,270,315,390,415,490};
__constant__ int E_t [15] = {0,16,32, 48,96,144,192,240,288, 336,416,496,576,656,736};

__device__ __forceinline__ double dfact(int n){
    const double F[9] = {1.0,1.0,2.0,6.0,24.0,120.0,720.0,5040.0,40320.0};
    return F[n];
}

__device__ float cg_single(int j1,int m1,int j2,int m2,int j,int m){
    if (m1 + m2 != m) return 0.0f;
    double pre = sqrt((2.0*j+1.0)*dfact(j+j1-j2)*dfact(j-j1+j2)*dfact(j1+j2-j)/dfact(j1+j2+j+1));
    pre *= sqrt(dfact(j+m)*dfact(j-m)*dfact(j1-m1)*dfact(j1+m1)*dfact(j2-m2)*dfact(j2+m2));
    int k0 = 0;
    if (j2-j-m1 > k0) k0 = j2-j-m1;
    if (j1+m2-j > k0) k0 = j1+m2-j;
    int k1 = j1+j2-j;
    if (j1-m1 < k1) k1 = j1-m1;
    if (j2+m2 < k1) k1 = j2+m2;
    double s = 0.0;
    for (int k = k0; k <= k1; ++k){
        double d = dfact(k)*dfact(j1+j2-j-k)*dfact(j1-m1-k)*dfact(j2+m2-k)*dfact(j-j2+m1+k)*dfact(j-j1-m2+k);
        s += ((k & 1) ? -1.0 : 1.0) / d;
    }
    return (float)(pre * s);
}

__device__ __forceinline__ void tfill_full(const float* __restrict__ A, const float* __restrict__ S,
                                           const float* __restrict__ CG, const unsigned short* __restrict__ TB,
                                           const unsigned char* __restrict__ TA, const unsigned short* __restrict__ TC,
                                           float* __restrict__ Tw, int lane){
    #pragma unroll 1
    for (int idx = lane; idx < 816; idx += 64){
        unsigned tbv = TB[idx];
        int c = tbv & 15, st = (tbv>>4) & 255, ct = tbv >> 12;
        float s = 0.f;
        for (int q = 0; q < ct; ++q){
            int ab = TA[st+q];
            s += A[(ab>>4)*16 + c] * S[ab & 15] * CG[TC[st+q]];
        }
        Tw[idx] = s;
    }
}

__device__ __forceinline__ void tfill_diag(const float* __restrict__ M,
                                           const float* __restrict__ CG, const unsigned short* __restrict__ TB,
                                           const unsigned char* __restrict__ TA, const unsigned short* __restrict__ TC,
                                           float* __restrict__ Tw, int lane){
    #pragma unroll 1
    for (int idx = lane; idx < 816; idx += 64){
        unsigned tbv = TB[idx];
        int c = tbv & 15, st = (tbv>>4) & 255, ct = tbv >> 12;
        float s = 0.f;
        for (int q = 0; q < ct; ++q){
            int ab = TA[st+q];
            s += M[(ab>>4)*16 + c] * M[(ab&15)*16 + c] * CG[TC[st+q]];
        }
        Tw[idx] = s;
    }
}

__device__ __forceinline__ float mix_out(const float* __restrict__ WT, const float* __restrict__ Tw, int o){
    int krow = o >> 4, co = o & 15;
    int l = krow == 0 ? 0 : (krow < 4 ? 1 : 2);
    int k = krow - (l==0?0:(l==1?1:4));
    int np = l==0?3:6;
    int tb = l==0?0:(l==1?48:336);
    int rb = l==0?0:(l==1?48:144);
    int dl = 2*l+1;
    float acc = 0.f;
    const float4* Wp = (const float4*)&WT[co*244 + rb];
    #pragma unroll 1
    for (int pq = 0; pq < np; ++pq){
        const float4* Tp = (const float4*)&Tw[tb + (pq*dl + k)*16];
        float4 a0=Tp[0],a1=Tp[1],a2=Tp[2],a3=Tp[3];
        float4 b0=Wp[pq*4],b1=Wp[pq*4+1],b2=Wp[pq*4+2],b3=Wp[pq*4+3];
        acc += a0.x*b0.x+a0.y*b0.y+a0.z*b0.z+a0.w*b0.w
             + a1.x*b1.x+a1.y*b1.y+a1.z*b1.z+a1.w*b1.w
             + a2.x*b2.x+a2.y*b2.y+a2.z*b2.z+a2.w*b2.w
             + a3.x*b3.x+a3.y*b3.y+a3.z*b3.z+a3.w*b3.w;
    }
    return acc;
}

// grid barrier: 256 blocks, single level, BOUNDED SPIN (deadlock -> wrong answer, not hang).
__device__ __forceinline__ void gbar(int* bar, int inst){
    __syncthreads();
    if (threadIdx.x == 0){
        __threadfence();
        int* cnt = bar + inst*16;
        int* flg = bar + inst*16 + 8;
        int a = __hip_atomic_fetch_add(cnt, 1, __ATOMIC_ACQ_REL, __HIP_MEMORY_SCOPE_AGENT);
        if (a == 255)
            __hip_atomic_store(flg, 1, __ATOMIC_RELEASE, __HIP_MEMORY_SCOPE_AGENT);
        long spins = 0;
        while (__hip_atomic_load(flg, __ATOMIC_ACQUIRE, __HIP_MEMORY_SCOPE_AGENT) == 0){
            __builtin_amdgcn_s_sleep(2);
            if (++spins > 200000000L) break;   // safety valve: ~seconds, << harness timeout
        }
        __threadfence();
    }
    __syncthreads();
}

// Single persistent kernel: 256 blocks x 512 threads, 16 nodes/block, 2 nodes/wave.
__global__ __launch_bounds__(512) void k_all(
    const float* __restrict__ v0, const float* __restrict__ v1, const float* __restrict__ v2,
    const float* __restrict__ rel_pos, const float* __restrict__ norms,
    const float* __restrict__ Wr0, const float* __restrict__ Wr1, const float* __restrict__ Wr2,
    const float* __restrict__ Wn0, const float* __restrict__ Wn1, const float* __restrict__ Wn2,
    float* __restrict__ out,
    float* __restrict__ wrsum_ws, float* __restrict__ rel,
    float* __restrict__ part0, float* __restrict__ part1, int* __restrict__ bar)
{
    __shared__ float CG[616];
    __shared__ unsigned short TB[816];
    __shared__ unsigned char TA[160];
    __shared__ unsigned short TC[160];
    __shared__ float WT[3904];           // [co*244+row]
    __shared__ float AL[16][144];        // verts -> mp -> nl -> verts
    __shared__ float SX[16][12];
    __shared__ unsigned char CN[16][128];
    __shared__ __align__(16) float TS[8][816];  // per-wave T; first 4608 floats double as panel stage
    __shared__ float RED[24];
    __shared__ float SCL[4];

    const int t = threadIdx.x, w = t >> 6, lane = t & 63;
    const int bid = blockIdx.x;
    const int node0 = bid * 16;
    const int batch = bid >> 3;
    const int n0 = w*2, n1 = w*2 + 1;

    // ================= Phase A0: tables, wrsum, sphx, verts, conn =================
    #pragma unroll 1
    for (int idx = t; idx < 615; idx += 512){
        int e = 0;
        while (e < 14 && idx >= E_cg[e+1]) e++;
        int l = E_l[e], l1 = E_l1[e], l2 = E_l2[e];
        int local = idx - E_cg[e];
        int dl = 2*l+1, d2 = 2*l2+1;
        int k  = local % dl;
        int r  = local / dl;
        int u  = r % d2;
        int i1 = r / d2;
        CG[idx] = cg_single(l1, i1-l1, l2, u-l2, l, k-l);
    }
    if (t < 51){   // term tables, parallel over (e,k) pairs
        int p = t, e = 0, k = 0;
        for (e = 0; e < 15; ++e){
            int dl = 2*E_l[e]+1;
            if (p < dl){ k = p; break; }
            p -= dl;
        }
        int st = 0; bool stop = false;
        for (int pe = 0; pe < 15 && !stop; ++pe){
            int l = E_l[pe], l1 = E_l1[pe], l2 = E_l2[pe], dl = 2*l+1;
            for (int kk = 0; kk < dl; ++kk){
                if (pe == e && kk == k){ stop = true; break; }
                int u0 = kk - l + l1 + l2;
                int lo = u0 - 2*l2; if (lo < 0) lo = 0;
                int hi = u0; if (hi > 2*l1) hi = 2*l1;
                if (hi >= lo) st += hi - lo + 1;
            }
        }
        int l = E_l[e], l1 = E_l1[e], l2 = E_l2[e], dl = 2*l+1, d2 = 2*l2+1;
        int ab = (l1==0?0:(l1==1?1:4)), sb = (l2==0?0:(l2==1?1:4));
        int u0 = k - l + l1 + l2;
        int lo = u0 - 2*l2; if (lo < 0) lo = 0;
        int hi = u0; if (hi > 2*l1) hi = 2*l1;
        int ct = (hi >= lo) ? (hi - lo + 1) : 0;
        int nt = st;
        for (int m = lo; m <= hi; ++m){
            int u = u0 - m;
            TA[nt] = (unsigned char)(((ab+m)<<4) | (sb+u));
            TC[nt] = (unsigned short)(E_cg[e] + (m*d2+u)*dl + k);
            nt++;
        }
        for (int c = 0; c < 16; ++c)
            TB[E_t[e] + k*16 + c] = (unsigned short)(c | (st<<4) | (ct<<12));
    }
    if (bid < 15){   // wrsum: 15 blocks x 512 = 7680 (both layers)
        int q = bid*512 + t;
        int layer = q / 3840;
        int r = q % 3840;
        int row = r >> 4, co = r & 15;
        const float* Wr; int pairs; int lrow;
        if (row < 48)       { Wr = Wr0; pairs = 3; lrow = row; }
        else if (row < 144) { Wr = Wr1; pairs = 6; lrow = row - 48; }
        else                { Wr = Wr2; pairs = 6; lrow = row - 144; }
        int pairIdx = lrow >> 4, c = lrow & 15;
        const float* base = Wr + (size_t)layer*pairs*4096 + (size_t)(pairIdx*256 + c*16)*16 + co;
        float s = 0.f;
        #pragma unroll
        for (int d = 0; d < 16; ++d) s += base[d*16];
        wrsum_ws[q] = s;
    }
    #pragma unroll 1
    for (int nn = 0; nn < 2; ++nn){   // sphx: 2 nodes per wave
        int n = w*2 + nn, gn = node0 + n;
        const float* rp = rel_pos + (size_t)gn * (NN*3);
        float a[9];
        #pragma unroll
        for (int i = 0; i < 9; ++i) a[i] = 0.f;
        #pragma unroll
        for (int rr = 0; rr < 2; ++rr){
            int j = lane + rr*64;
            float x = rp[j*3], y = rp[j*3+1], z = rp[j*3+2];
            float rn = sqrtf(x*x+y*y+z*z) + 1e-6f;
            x /= rn; y /= rn; z /= rn;
            a[0] += 0.28209479f;
            a[1] += 0.48860251f*y; a[2] += 0.48860251f*z; a[3] += 0.48860251f*x;
            a[4] += 1.09254843f*x*y; a[5] += 1.09254843f*y*z;
            a[6] += 0.31539157f*(3.f*z*z-1.f);
            a[7] += 1.09254843f*x*z; a[8] += 0.54627422f*(x*x-y*y);
        }
        #pragma unroll
        for (int i = 0; i < 9; ++i){
            float vv = a[i];
            for (int off = 32; off; off >>= 1) vv += __shfl_down(vv, off, 64);
            if (lane == 0) SX[n][i] = vv;
        }
    }
    #pragma unroll 1
    for (int i = t; i < 2304; i += 512){   // verts
        int n = i/144, o = i%144, gn = node0+n;
        float v;
        if (o < 16)      v = v0[(size_t)gn*16 + o];
        else if (o < 64) v = v1[(size_t)gn*48 + (o-16)];
        else             v = v2[(size_t)gn*80 + (o-64)];
        AL[n][o] = v;
    }
    #pragma unroll 1
    for (int i = t; i < 2048; i += 512){   // conn
        int n = i >> 7, j = i & 127;
        CN[n][j] = (norms[(size_t)(node0+n)*NN + j] < 0.5f) ? 1 : 0;
    }
    gbar(bar, 0);

    // ================= Phase A1: rel layer 0 =================
    #pragma unroll 1
    for (int i = t; i < 3840; i += 512) WT[(i&15)*244 + (i>>4)] = wrsum_ws[i];
    __syncthreads();
    #pragma unroll 1
    for (int nn = 0; nn < 2; ++nn){
        int n = w*2 + nn, gn = node0 + n;
        tfill_full(&AL[n][0], &SX[n][0], CG, TB, TA, TC, &TS[w][0], lane);
        __syncthreads();
        float* relw = rel + (size_t)gn * 144;
        #pragma unroll 1
        for (int o = lane; o < 144; o += 64) relw[o] = mix_out(WT, &TS[w][0], o);
        __syncthreads();
    }
    gbar(bar, 1);

    // ================= layers =================
    #pragma unroll 1
    for (int layer = 0; layer < 2; ++layer){
        float* part = layer == 0 ? part0 : part1;
        // ---- mp phase: message pass + diag CG + Wn mix -> nl in AL; partials -> part ----
        #pragma unroll 1
        for (int i = t; i < 768;  i += 512) WT[(i&15)*244 + (i>>4)]       = Wn0[(size_t)layer*768  + i];
        #pragma unroll 1
        for (int i = t; i < 1536; i += 512) WT[(i&15)*244 + 48  + (i>>4)] = Wn1[(size_t)layer*1536 + i];
        #pragma unroll 1
        for (int i = t; i < 1536; i += 512) WT[(i&15)*244 + 144 + (i>>4)] = Wn2[(size_t)layer*1536 + i];
        {
            const float4* r4 = (const float4*)(rel + (size_t)batch * (NN*144));
            float a00=0.f,a01=0.f,a02=0.f, a10=0.f,a11=0.f,a12=0.f;
            float4* s4 = (float4*)&TS[0][0];
            #pragma unroll 1
            for (int r = 0; r < 4; ++r){
                __syncthreads();
                #pragma unroll 1
                for (int i = t; i < 1152; i += 512) s4[i] = r4[r*1152 + i];
                __syncthreads();
                #pragma unroll 4
                for (int jj = 0; jj < 32; ++jj){
                    float c0 = (float)CN[n0][r*32 + jj];
                    float c1 = (float)CN[n1][r*32 + jj];
                    const float* row = &TS[0][0] + jj*144;
                    float x0 = row[lane], x1 = row[64 + lane];
                    a00 += c0*x0; a01 += c0*x1;
                    a10 += c1*x0; a11 += c1*x1;
                    if (lane < 16){
                        float x2 = row[128 + lane];
                        a02 += c0*x2; a12 += c1*x2;
                    }
                }
            }
            __syncthreads();
            AL[n0][lane] = a00; AL[n0][64+lane] = a01; if (lane < 16) AL[n0][128+lane] = a02;
            AL[n1][lane] = a10; AL[n1][64+lane] = a11; if (lane < 16) AL[n1][128+lane] = a12;
            __syncthreads();
        }
        float pz0 = 0.f, pz1 = 0.f, pz2 = 0.f;
        #pragma unroll 1
        for (int nn = 0; nn < 2; ++nn){
            int n = w*2 + nn;
            tfill_diag(&AL[n][0], CG, TB, TA, TC, &TS[w][0], lane);
            __syncthreads();
            #pragma unroll 1
            for (int o = lane; o < 144; o += 64){
                float acc = mix_out(WT, &TS[w][0], o);
                AL[n][o] = acc;
                float sq = acc*acc;
                int krow = o >> 4;
                if (krow == 0) pz0 += sq; else if (krow < 4) pz1 += sq; else pz2 += sq;
            }
            __syncthreads();
        }
        for (int off = 32; off; off >>= 1){
            pz0 += __shfl_down(pz0, off, 64);
            pz1 += __shfl_down(pz1, off, 64);
            pz2 += __shfl_down(pz2, off, 64);
        }
        if (lane == 0){ RED[w] = pz0; RED[8+w] = pz1; RED[16+w] = pz2; }
        __syncthreads();
        if (t < 3){
            float s = 0.f;
            #pragma unroll
            for (int q = 0; q < 8; ++q) s += RED[t*8 + q];
            part[bid*3 + t] = s;
        }
        gbar(bar, 2 + layer*2);

        // ---- norm phase: global scale, normalize AL, scalars out; if layer0 also rel L1 ----
        if (t < 4) SCL[t] = 0.f;
        __syncthreads();
        #pragma unroll 1
        for (int i = t; i < 768; i += 512) atomicAdd(&SCL[i % 3], part[i]);
        __syncthreads();
        if (t < 3) SCL[t] = 16.f / ((2*t+1) * sqrtf(SCL[t]));
        __syncthreads();
        {
            float s0 = SCL[0], s1 = SCL[1], s2 = SCL[2];
            #pragma unroll 1
            for (int i = t; i < 2304; i += 512){
                int n = i/144, o = i%144, krow = o >> 4;
                AL[n][o] *= (krow == 0 ? s0 : (krow < 4 ? s1 : s2));
            }
        }
        __syncthreads();
        if (t < 256){
            int n = t >> 4, c = t & 15;
            float s0 = AL[n][c];
            float sn0 = s0*s0, sn1 = 0.f, sn2 = 0.f;
            #pragma unroll
            for (int k = 0; k < 3; ++k){ float v = AL[n][16 + k*16 + c]; sn1 += v*v; }
            #pragma unroll
            for (int k = 0; k < 5; ++k){ float v = AL[n][64 + k*16 + c]; sn2 += v*v; }
            float* ob = out + (size_t)(node0+n)*128 + layer*64;
            ob[c] = s0; ob[16+c] = sn0; ob[32+c] = sn1; ob[48+c] = sn2;
        }
        if (layer == 0){
            #pragma unroll 1
            for (int i = t; i < 3840; i += 512) WT[(i&15)*244 + (i>>4)] = wrsum_ws[3840 + i];
            __syncthreads();
            #pragma unroll 1
            for (int nn = 0; nn < 2; ++nn){
                int n = w*2 + nn, gn = node0 + n;
                tfill_full(&AL[n][0], &SX[n][0], CG, TB, TA, TC, &TS[w][0], lane);
                __syncthreads();
                float* relw = rel + (size_t)gn * 144;
                #pragma unroll 1
                for (int o = lane; o < 144; o += 64) relw[o] = mix_out(WT, &TS[w][0], o);
                __syncthreads();
            }
            gbar(bar, 3);
        }
    }
}

extern "C" void kernel_launch(void* const* d_in, const int* in_sizes, int n_in,
                              void* d_out, int out_size, void* d_ws, size_t ws_size,
                              hipStream_t stream){
    const float* v0      = (const float*)d_in[0];
    const float* v1      = (const float*)d_in[1];
    const float* v2      = (const float*)d_in[2];
    const float* rel_pos = (const float*)d_in[3];
    const float* norms   = (const float*)d_in[4];
    const float* Wr0     = (const float*)d_in[5];
    const float* Wr1     = (const float*)d_in[6];
    const float* Wr2     = (const float*)d_in[7];
    const float* Wn0     = (const float*)d_in[8];
    const float* Wn1     = (const float*)d_in[9];
    const float* Wn2     = (const float*)d_in[10];
    float* out = (float*)d_out;
    float* ws  = (float*)d_ws;

    float* wrsum = ws + 0;        // 7680
    float* rel   = ws + 7680;     // 4096*144 = 589824
    float* part0 = ws + 597504;   // 768
    float* part1 = ws + 598272;   // 768
    int*   bar   = (int*)(ws + 599040);  // 5*16 = 80 ints

    hipMemsetAsync(bar, 0, 80*sizeof(int), stream);
    k_all<<<256, 512, 0, stream>>>(v0, v1, v2, rel_pos, norms,
                                   Wr0, Wr1, Wr2, Wn0, Wn1, Wn2,
                                   out, wrsum, rel, part0, part1, bar);
}